// Round 4
// baseline (352.442 us; speedup 1.0000x reference)
//
#include <hip/hip_runtime.h>

typedef __bf16 bf16x8 __attribute__((ext_vector_type(8)));
typedef float floatx4 __attribute__((ext_vector_type(4)));
typedef float floatx16 __attribute__((ext_vector_type(16)));
typedef unsigned int u32;

#define BB 4
#define CC 256
#define NN 4096

__device__ __forceinline__ unsigned short f2bf(float f) {
  union { float f; unsigned u; } v; v.f = f;
  unsigned r = v.u + 0x7fffu + ((v.u >> 16) & 1u);
  return (unsigned short)(r >> 16);
}

__device__ __forceinline__ float bf2f(unsigned short s) {
  union { unsigned u; float f; } v; v.u = ((u32)s) << 16;
  return v.f;
}

// ---------------- GroupNorm stats: 128 blocks, each reduces a contiguous 32768-float group ----
__global__ __launch_bounds__(256) void gn_stats(const float* __restrict__ x, float* __restrict__ mr) {
  int bg = blockIdx.x;
  const float* p = x + (size_t)bg * 32768;
  int t = threadIdx.x;
  float s = 0.f, q = 0.f;
#pragma unroll
  for (int it = 0; it < 32; ++it) {
    float4 v = *(const float4*)(p + it * 1024 + t * 4);
    s += v.x + v.y + v.z + v.w;
    q += v.x * v.x + v.y * v.y + v.z * v.z + v.w * v.w;
  }
#pragma unroll
  for (int off = 1; off < 64; off <<= 1) {
    s += __shfl_xor(s, off, 64);
    q += __shfl_xor(q, off, 64);
  }
  __shared__ float red[8];
  int w = t >> 6;
  if ((t & 63) == 0) { red[w] = s; red[4 + w] = q; }
  __syncthreads();
  if (t == 0) {
    float S = red[0] + red[1] + red[2] + red[3];
    float Q = red[4] + red[5] + red[6] + red[7];
    float mean = S * (1.f / 32768.f);
    float var = Q * (1.f / 32768.f) - mean * mean;
    mr[bg] = mean;
    mr[128 + bg] = rsqrtf(var + 1e-5f);
  }
}

// ---------------- normalize + transpose to normed[b][n][c] bf16 ----------------
__global__ __launch_bounds__(256) void gn_apply(const float* __restrict__ x, const float* __restrict__ mr,
                                                const float* __restrict__ gamma, const float* __restrict__ beta,
                                                unsigned short* __restrict__ normed) {
  int bid = blockIdx.x;              // b * 4(ctile) * 64(ntile)
  int nt = bid & 63;
  int ct = (bid >> 6) & 3;
  int b = bid >> 8;
  int c0 = ct * 64, n0 = nt * 64;
  __shared__ unsigned short T[64][80];   // [n][c], padded
  int t = threadIdx.x;
#pragma unroll
  for (int it = 0; it < 4; ++it) {
    int idx = it * 256 + t;
    int cl = idx >> 4;
    int n4 = (idx & 15) * 4;
    int c = c0 + cl;
    int bg = b * 32 + (c >> 3);
    float mean = mr[bg], rstd = mr[128 + bg];
    float sc = rstd * gamma[c];
    float sh = beta[c] - mean * sc;
    float4 v = *(const float4*)(x + ((size_t)(b * CC + c)) * NN + n0 + n4);
    T[n4 + 0][cl] = f2bf(v.x * sc + sh);
    T[n4 + 1][cl] = f2bf(v.y * sc + sh);
    T[n4 + 2][cl] = f2bf(v.z * sc + sh);
    T[n4 + 3][cl] = f2bf(v.w * sc + sh);
  }
  __syncthreads();
#pragma unroll
  for (int it = 0; it < 2; ++it) {
    int idx = it * 256 + t;
    int nl = idx >> 3, ck = idx & 7;
    uint4 val;
    unsigned short* pv = (unsigned short*)&val;
#pragma unroll
    for (int j = 0; j < 8; ++j) pv[j] = T[nl][ck * 8 + j];
    *(uint4*)(normed + ((size_t)b * NN + n0 + nl) * CC + c0 + ck * 8) = val;
  }
}

// ---------------- weight fp32 -> bf16 (q rows pre-scaled by log2(e)/sqrt(C)) ----------------
__global__ __launch_bounds__(256) void wconv(const float* __restrict__ wqkv, const float* __restrict__ wproj,
                                             unsigned short* __restrict__ wq_bf, unsigned short* __restrict__ wp_bf) {
  int i = blockIdx.x * 256 + threadIdx.x;      // 1024 blocks -> 262144
  if (i < 196608) {
    float v = wqkv[i];
    if (i < 65536) v *= 0.090168440055560213f;  // log2(e)/16
    wq_bf[i] = f2bf(v);
  } else {
    int j = i - 196608;
    wp_bf[j] = f2bf(wproj[j]);
  }
}

// ---------------- B^T GEMM: C[M][Nc] = A[M][256] * B[Nc][256]^T  (128x128 tiles) ----------------
template <int RESID>
__global__ __launch_bounds__(256) void gemm_bt(const unsigned short* __restrict__ A,
                                               const unsigned short* __restrict__ Bm,
                                               void* __restrict__ Cout, const float* __restrict__ resid,
                                               int mtiles, int ldc,
                                               long sA, long sB, long sC, long sR) {
  int mt = blockIdx.x % mtiles;
  int nt = blockIdx.x / mtiles;
  int b = blockIdx.y;
  int m0 = mt * 128, n0 = nt * 128;
  __shared__ unsigned short As[128][72];
  __shared__ unsigned short Bs[128][72];
  int t = threadIdx.x;
  int w = t >> 6, lane = t & 63;
  int l16 = lane & 15, quad = lane >> 4;
  int wr = w >> 1, wc = w & 1;
  const unsigned short* Ab = A + (size_t)b * sA + (size_t)m0 * 256;
  const unsigned short* Bb = Bm + (size_t)b * sB + (size_t)n0 * 256;
  floatx4 acc[4][4];
#pragma unroll
  for (int m = 0; m < 4; ++m)
#pragma unroll
    for (int n = 0; n < 4; ++n)
#pragma unroll
      for (int r = 0; r < 4; ++r) acc[m][n][r] = 0.f;

  for (int kb = 0; kb < 4; ++kb) {
    __syncthreads();
#pragma unroll
    for (int i = 0; i < 4; ++i) {
      int idx = i * 256 + t;
      int r = idx >> 3, ck = idx & 7;
      *(uint4*)&As[r][ck * 8] = *(const uint4*)(Ab + (size_t)r * 256 + kb * 64 + ck * 8);
      *(uint4*)&Bs[r][ck * 8] = *(const uint4*)(Bb + (size_t)r * 256 + kb * 64 + ck * 8);
    }
    __syncthreads();
#pragma unroll
    for (int kk = 0; kk < 2; ++kk) {
      bf16x8 af[4], bfr[4];
#pragma unroll
      for (int m = 0; m < 4; ++m) af[m] = *(const bf16x8*)&As[wr * 64 + m * 16 + l16][kk * 32 + quad * 8];
#pragma unroll
      for (int n = 0; n < 4; ++n) bfr[n] = *(const bf16x8*)&Bs[wc * 64 + n * 16 + l16][kk * 32 + quad * 8];
#pragma unroll
      for (int m = 0; m < 4; ++m)
#pragma unroll
        for (int n = 0; n < 4; ++n)
          acc[m][n] = __builtin_amdgcn_mfma_f32_16x16x32_bf16(af[m], bfr[n], acc[m][n], 0, 0, 0);
    }
  }
  size_t cb = (size_t)b * sC;
  size_t rb = (size_t)b * sR;
#pragma unroll
  for (int m = 0; m < 4; ++m)
#pragma unroll
    for (int n = 0; n < 4; ++n)
#pragma unroll
      for (int r = 0; r < 4; ++r) {
        int row = m0 + wr * 64 + m * 16 + quad * 4 + r;
        int col = n0 + wc * 64 + n * 16 + l16;
        size_t idx = (size_t)row * ldc + col;
        if (RESID)
          ((float*)Cout)[cb + idx] = acc[m][n][r] + resid[rb + idx];
        else
          ((unsigned short*)Cout)[cb + idx] = f2bf(acc[m][n][r]);
      }
}

// ---------------- fused attention v4: K-split (2 blocks per Q-tile), single-smem-array LDS ----
// grid 512 = 2 blocks/CU (launch_bounds(256,2)). Block = (b, qt, kh): Q rows [qt*64,+64),
// K/V rows [kh*2048,+2048). 4 waves (wr = j-half, wc = i-half). Per iter: stage K/V into
// padded conflict-free LDS, S^T = K.Q^T (lane = i), P = exp2 in-register, hi-half shfl
// exchange -> A-frag, O += P.V. Emits unnormalized bf16 O-partial + fp32 l-partial.
// NOTE: all LDS lives in ONE char array — epilogue float overlay must not assume the
// compiler keeps separate __shared__ arrays in declaration order (v3 bug).
__global__ __launch_bounds__(256, 2) void attn(const unsigned short* __restrict__ qk,   // [B][N][512] (q|k)
                                               const unsigned short* __restrict__ vbuf, // [B][C][N]
                                               unsigned short* __restrict__ opart0,     // [B][N][C] bf16 (kh=0)
                                               unsigned short* __restrict__ opart1,     // [B][N][C] bf16 (kh=1)
                                               float* __restrict__ lpart) {             // [B*2][N]
  __shared__ __attribute__((aligned(16))) char smem[71168];
  unsigned short* Ks = (unsigned short*)smem;            // [64 j][264] = 33792 B
  unsigned short* VT = (unsigned short*)(smem + 33792);  // [256 c][72] = 36864 B
  float* Lred = (float*)(smem + 70656);                  // [2 wr][2 wc][32 i] = 512 B

  int xcd = blockIdx.x & 7, slot = blockIdx.x >> 3;
  int b = xcd >> 1;
  int kh = xcd & 1;
  int qt = slot;
  int i0 = qt * 64;
  int k0 = kh * 32;

  int t = threadIdx.x, w = t >> 6, l = t & 63;
  int l31 = l & 31, hi = l >> 5;
  int wr = w >> 1, wc = w & 1;

  const size_t bqk = (size_t)b * NN * 512;
  const size_t bv = (size_t)b * CC * NN;

  // Q fragments (B-operand): lane = i = wc*32+l31, elems = c = ks*16 + hi*8 + 0..7
  bf16x8 qreg[16];
  {
    const unsigned short* qp = qk + bqk + (size_t)(i0 + wc * 32 + l31) * 512 + hi * 8;
#pragma unroll
    for (int ks = 0; ks < 16; ++ks)
      qreg[ks] = *(const bf16x8*)(qp + ks * 16);
  }

  floatx16 oacc[8];
#pragma unroll
  for (int cf = 0; cf < 8; ++cf)
#pragma unroll
    for (int r = 0; r < 16; ++r) oacc[cf][r] = 0.f;
  float lacc = 0.f;

  const int kfoff = (wr * 32 + l31) * 264 + hi * 8;
  const int vtoff = wr * 32 + hi * 8;

  for (int kt = k0; kt < k0 + 32; ++kt) {
    __syncthreads();
    // stage K-tile [64 j][256 c] and V-tile [256 c][64 j]
    {
      const unsigned short* kg = qk + bqk + ((size_t)kt * 64) * 512 + 256;
#pragma unroll
      for (int it = 0; it < 8; ++it) {
        int idx = it * 256 + t;
        int r = idx >> 5, ck = idx & 31;
        *(uint4*)&Ks[r * 264 + ck * 8] = *(const uint4*)(kg + (size_t)r * 512 + ck * 8);
      }
      const unsigned short* vg = vbuf + bv + (size_t)kt * 64;
#pragma unroll
      for (int it = 0; it < 8; ++it) {
        int idx = it * 256 + t;
        int r = idx >> 3, ck = idx & 7;
        *(uint4*)&VT[r * 72 + ck * 8] = *(const uint4*)(vg + (size_t)r * NN + ck * 8);
      }
    }
    __syncthreads();

    // S^T = K . Q^T  (D[m=j][n=i]; lane = i)
    floatx16 st;
#pragma unroll
    for (int r = 0; r < 16; ++r) st[r] = 0.f;
#pragma unroll
    for (int ks = 0; ks < 16; ++ks) {
      bf16x8 kf = *(const bf16x8*)&Ks[kfoff + ks * 16];
      st = __builtin_amdgcn_mfma_f32_32x32x16_bf16(kf, qreg[ks], st, 0, 0, 0);
    }

    // P = exp2(S^T), pack bf16 pairs along j
    u32 pr[8];
#pragma unroll
    for (int k2 = 0; k2 < 8; ++k2) {
      float p0 = __builtin_amdgcn_exp2f(st[2 * k2]);
      float p1 = __builtin_amdgcn_exp2f(st[2 * k2 + 1]);
      lacc += p0 + p1;
      pr[k2] = (u32)f2bf(p0) | ((u32)f2bf(p1) << 16);
    }

    // rearrange into PV A-fragments (j = wr*32 + s*16 + hi*8 + 0..7) via hi-half exchange
    union U { u32 u[4]; bf16x8 v; } a0, a1;
    {
      u32 sA = hi ? pr[0] : pr[2], sB = hi ? pr[1] : pr[3];
      u32 rA = (u32)__shfl_xor((int)sA, 32, 64);
      u32 rB = (u32)__shfl_xor((int)sB, 32, 64);
      a0.u[0] = hi ? rA : pr[0]; a0.u[1] = hi ? rB : pr[1];
      a0.u[2] = hi ? pr[2] : rA; a0.u[3] = hi ? pr[3] : rB;
      sA = hi ? pr[4] : pr[6]; sB = hi ? pr[5] : pr[7];
      rA = (u32)__shfl_xor((int)sA, 32, 64);
      rB = (u32)__shfl_xor((int)sB, 32, 64);
      a1.u[0] = hi ? rA : pr[4]; a1.u[1] = hi ? rB : pr[5];
      a1.u[2] = hi ? pr[6] : rA; a1.u[3] = hi ? pr[7] : rB;
    }

    // O_partial += P . V  (B-frag: lane = c = cf*32+l31, elems = j)
#pragma unroll
    for (int cf = 0; cf < 8; ++cf) {
      const unsigned short* vp = &VT[(cf * 32 + l31) * 72 + vtoff];
      bf16x8 v0 = *(const bf16x8*)vp;
      oacc[cf] = __builtin_amdgcn_mfma_f32_32x32x16_bf16(a0.v, v0, oacc[cf], 0, 0, 0);
      bf16x8 v1 = *(const bf16x8*)(vp + 16);
      oacc[cf] = __builtin_amdgcn_mfma_f32_32x32x16_bf16(a1.v, v1, oacc[cf], 0, 0, 0);
    }
  }

  // ---- epilogue: combine 4 waves' partials in LDS, store bf16 O-partial + fp32 l-partial ----
  float l2 = lacc + __shfl_xor(lacc, 32, 64);
  __syncthreads();
  if (hi == 0) Lred[(wr * 2 + wc) * 32 + l31] = l2;
  float* Of = (float*)smem;   // [wc][i_local 32][c 256] floats = 65536 B, inside Ks+VT (70656 B)
  if (wr == 1) {
#pragma unroll
    for (int cf = 0; cf < 8; ++cf)
#pragma unroll
      for (int r = 0; r < 16; ++r) {
        int il = (r & 3) + 8 * (r >> 2) + 4 * hi;
        Of[wc * 8192 + il * 256 + cf * 32 + l31] = oacc[cf][r];
      }
  }
  __syncthreads();
  unsigned short* ops = kh ? opart1 : opart0;
  size_t pbo = (size_t)b * NN + i0;
  size_t pbl = (size_t)(b * 2 + kh) * NN + i0;
  if (t < 64) lpart[pbl + t] = Lred[(t >> 5) * 32 + (t & 31)] + Lred[(2 + (t >> 5)) * 32 + (t & 31)];
  if (wr == 0) {
#pragma unroll
    for (int cf = 0; cf < 8; ++cf)
#pragma unroll
      for (int r = 0; r < 16; ++r) {
        int il = (r & 3) + 8 * (r >> 2) + 4 * hi;
        Of[wc * 8192 + il * 256 + cf * 32 + l31] += oacc[cf][r];
      }
  }
  __syncthreads();
#pragma unroll
  for (int it = 0; it < 8; ++it) {
    int chunk = it * 256 + t;          // 2048 chunks of 8 elems
    int i = chunk >> 5;
    int cc = (chunk & 31) * 8;
    int base = (i >> 5) * 8192 + (i & 31) * 256 + cc;
    floatx4 v0 = *(const floatx4*)&Of[base];
    floatx4 v1 = *(const floatx4*)&Of[base + 4];
    union { unsigned short us[8]; uint4 q; } o;
#pragma unroll
    for (int j = 0; j < 4; ++j) {
      o.us[j] = f2bf(v0[j]);
      o.us[4 + j] = f2bf(v1[j]);
    }
    *(uint4*)(ops + (pbo + i) * CC + cc) = o.q;
  }
}

// ---------------- combine the two K-half partials: obuf = (O0+O1)/(l0+l1) ----------------
__global__ __launch_bounds__(256) void attn_combine(const unsigned short* __restrict__ op0,
                                                    const unsigned short* __restrict__ op1,
                                                    const float* __restrict__ lp,
                                                    unsigned short* __restrict__ obuf) {
  int gid = blockIdx.x * 256 + threadIdx.x;   // 524288 threads, 8 elems each
  int e = gid * 8;
  int b = e >> 20;
  int inner = e & 1048575;
  int n = inner >> 8;
  float linv = 1.f / (lp[b * 8192 + n] + lp[b * 8192 + 4096 + n]);
  size_t off = (size_t)b * 1048576 + inner;
  uint4 u0 = *(const uint4*)(op0 + off);
  uint4 u1 = *(const uint4*)(op1 + off);
  const unsigned short* a = (const unsigned short*)&u0;
  const unsigned short* c = (const unsigned short*)&u1;
  union { unsigned short us[8]; uint4 q; } o;
#pragma unroll
  for (int j = 0; j < 8; ++j)
    o.us[j] = f2bf((bf2f(a[j]) + bf2f(c[j])) * linv);
  *(uint4*)(obuf + e) = o.q;
}

extern "C" void kernel_launch(void* const* d_in, const int* in_sizes, int n_in,
                              void* d_out, int out_size, void* d_ws, size_t ws_size,
                              hipStream_t stream) {
  const float* x     = (const float*)d_in[0];
  // d_in[1] = t (unused)
  const float* gamma = (const float*)d_in[2];
  const float* beta  = (const float*)d_in[3];
  const float* wqkv  = (const float*)d_in[4];
  const float* wproj = (const float*)d_in[5];
  float* out = (float*)d_out;

  // Workspace layout (max 42,468,352 B — same footprint proven in rounds 1-2):
  //   [0,1024)            mr (dead after gn_apply)
  //   [1024, 394240)      wq_bf 384 KB (dead after v-GEMM) — lpart (128 KB) overlays @1024
  //   [394240, 525312)    wp_bf 128 KB (live until proj GEMM)
  //   [525312, 8913920)   normed 8 MB (dead after v-GEMM) — opart0 overlays
  //   [8913920, 25691136) qkbuf 16 MB (dead after attn)   — obuf overlays
  //   [25691136,34079744) vbuf 8 MB
  //   [34079744,42468352) opart1 8 MB
  char* p = (char*)d_ws;
  float* mr               = (float*)(p + 0);
  unsigned short* wq_bf   = (unsigned short*)(p + 1024);
  unsigned short* wp_bf   = (unsigned short*)(p + 394240);
  unsigned short* normed  = (unsigned short*)(p + 525312);
  unsigned short* qkbuf   = (unsigned short*)(p + 8913920);
  unsigned short* vbuf    = (unsigned short*)(p + 25691136);
  unsigned short* opart1  = (unsigned short*)(p + 34079744);
  unsigned short* opart0  = normed;                            // overlay (normed dead after v-GEMM)
  float* lpart            = (float*)(p + 1024);                // overlay (wq_bf dead after v-GEMM)
  unsigned short* obuf    = qkbuf;                             // overlay (qkbuf dead after attn)
  unsigned short* wv_bf   = wq_bf + 512 * 256;

  wconv<<<1024, 256, 0, stream>>>(wqkv, wproj, wq_bf, wp_bf);
  gn_stats<<<128, 256, 0, stream>>>(x, mr);
  gn_apply<<<1024, 256, 0, stream>>>(x, mr, gamma, beta, normed);
  // qk[b][n][o] = normed[b][n][:] . wqkv[o][:]  (o<512)
  gemm_bt<0><<<dim3(128, 4), 256, 0, stream>>>(normed, wq_bf, qkbuf, nullptr,
                                               32, 512, (long)NN * CC, 0L, (long)NN * 512, 0L);
  // v[b][c][n] = wv[c][:] . normed[b][n][:]
  gemm_bt<0><<<dim3(64, 4), 256, 0, stream>>>(wv_bf, normed, vbuf, nullptr,
                                              2, 4096, 0L, (long)NN * CC, (long)CC * NN, 0L);
  attn<<<512, 256, 0, stream>>>(qkbuf, vbuf, opart0, opart1, lpart);
  attn_combine<<<2048, 256, 0, stream>>>(opart0, opart1, lpart, obuf);
  // out[b][co][n] = wproj[co][:] . obuf[b][n][:] + x[b][co][n]
  gemm_bt<1><<<dim3(64, 4), 256, 0, stream>>>(wp_bf, obuf, out, x,
                                              2, 4096, 0L, (long)NN * CC, (long)CC * NN, (long)CC * NN);
}

// Round 5
// 205.525 us; speedup vs baseline: 1.7148x; 1.7148x over previous
//
#include <hip/hip_runtime.h>

typedef __bf16 bf16x8 __attribute__((ext_vector_type(8)));
typedef float floatx4 __attribute__((ext_vector_type(4)));
typedef float floatx16 __attribute__((ext_vector_type(16)));
typedef unsigned int u32;

#define BB 4
#define CC 256
#define NN 4096

__device__ __forceinline__ unsigned short f2bf(float f) {
  union { float f; unsigned u; } v; v.f = f;
  unsigned r = v.u + 0x7fffu + ((v.u >> 16) & 1u);
  return (unsigned short)(r >> 16);
}

__device__ __forceinline__ float bf2f(unsigned short s) {
  union { unsigned u; float f; } v; v.u = ((u32)s) << 16;
  return v.f;
}

// ---------------- GroupNorm stats: 128 blocks, each reduces a contiguous 32768-float group ----
__global__ __launch_bounds__(256) void gn_stats(const float* __restrict__ x, float* __restrict__ mr) {
  int bg = blockIdx.x;
  const float* p = x + (size_t)bg * 32768;
  int t = threadIdx.x;
  float s = 0.f, q = 0.f;
#pragma unroll
  for (int it = 0; it < 32; ++it) {
    float4 v = *(const float4*)(p + it * 1024 + t * 4);
    s += v.x + v.y + v.z + v.w;
    q += v.x * v.x + v.y * v.y + v.z * v.z + v.w * v.w;
  }
#pragma unroll
  for (int off = 1; off < 64; off <<= 1) {
    s += __shfl_xor(s, off, 64);
    q += __shfl_xor(q, off, 64);
  }
  __shared__ float red[8];
  int w = t >> 6;
  if ((t & 63) == 0) { red[w] = s; red[4 + w] = q; }
  __syncthreads();
  if (t == 0) {
    float S = red[0] + red[1] + red[2] + red[3];
    float Q = red[4] + red[5] + red[6] + red[7];
    float mean = S * (1.f / 32768.f);
    float var = Q * (1.f / 32768.f) - mean * mean;
    mr[bg] = mean;
    mr[128 + bg] = rsqrtf(var + 1e-5f);
  }
}

// ---------------- normalize + transpose to normed[b][n][c] bf16 ----------------
__global__ __launch_bounds__(256) void gn_apply(const float* __restrict__ x, const float* __restrict__ mr,
                                                const float* __restrict__ gamma, const float* __restrict__ beta,
                                                unsigned short* __restrict__ normed) {
  int bid = blockIdx.x;              // b * 4(ctile) * 64(ntile)
  int nt = bid & 63;
  int ct = (bid >> 6) & 3;
  int b = bid >> 8;
  int c0 = ct * 64, n0 = nt * 64;
  __shared__ unsigned short T[64][80];   // [n][c], padded
  int t = threadIdx.x;
#pragma unroll
  for (int it = 0; it < 4; ++it) {
    int idx = it * 256 + t;
    int cl = idx >> 4;
    int n4 = (idx & 15) * 4;
    int c = c0 + cl;
    int bg = b * 32 + (c >> 3);
    float mean = mr[bg], rstd = mr[128 + bg];
    float sc = rstd * gamma[c];
    float sh = beta[c] - mean * sc;
    float4 v = *(const float4*)(x + ((size_t)(b * CC + c)) * NN + n0 + n4);
    T[n4 + 0][cl] = f2bf(v.x * sc + sh);
    T[n4 + 1][cl] = f2bf(v.y * sc + sh);
    T[n4 + 2][cl] = f2bf(v.z * sc + sh);
    T[n4 + 3][cl] = f2bf(v.w * sc + sh);
  }
  __syncthreads();
#pragma unroll
  for (int it = 0; it < 2; ++it) {
    int idx = it * 256 + t;
    int nl = idx >> 3, ck = idx & 7;
    uint4 val;
    unsigned short* pv = (unsigned short*)&val;
#pragma unroll
    for (int j = 0; j < 8; ++j) pv[j] = T[nl][ck * 8 + j];
    *(uint4*)(normed + ((size_t)b * NN + n0 + nl) * CC + c0 + ck * 8) = val;
  }
}

// ---------------- weight fp32 -> bf16 (q rows pre-scaled by log2(e)/sqrt(C)) ----------------
__global__ __launch_bounds__(256) void wconv(const float* __restrict__ wqkv, const float* __restrict__ wproj,
                                             unsigned short* __restrict__ wq_bf, unsigned short* __restrict__ wp_bf) {
  int i = blockIdx.x * 256 + threadIdx.x;      // 1024 blocks -> 262144
  if (i < 196608) {
    float v = wqkv[i];
    if (i < 65536) v *= 0.090168440055560213f;  // log2(e)/16
    wq_bf[i] = f2bf(v);
  } else {
    int j = i - 196608;
    wp_bf[j] = f2bf(wproj[j]);
  }
}

// ---------------- B^T GEMM: C[M][Nc] = A[M][256] * B[Nc][256]^T  (128x128 tiles) ----------------
template <int RESID>
__global__ __launch_bounds__(256) void gemm_bt(const unsigned short* __restrict__ A,
                                               const unsigned short* __restrict__ Bm,
                                               void* __restrict__ Cout, const float* __restrict__ resid,
                                               int mtiles, int ldc,
                                               long sA, long sB, long sC, long sR) {
  int mt = blockIdx.x % mtiles;
  int nt = blockIdx.x / mtiles;
  int b = blockIdx.y;
  int m0 = mt * 128, n0 = nt * 128;
  __shared__ unsigned short As[128][72];
  __shared__ unsigned short Bs[128][72];
  int t = threadIdx.x;
  int w = t >> 6, lane = t & 63;
  int l16 = lane & 15, quad = lane >> 4;
  int wr = w >> 1, wc = w & 1;
  const unsigned short* Ab = A + (size_t)b * sA + (size_t)m0 * 256;
  const unsigned short* Bb = Bm + (size_t)b * sB + (size_t)n0 * 256;
  floatx4 acc[4][4];
#pragma unroll
  for (int m = 0; m < 4; ++m)
#pragma unroll
    for (int n = 0; n < 4; ++n)
#pragma unroll
      for (int r = 0; r < 4; ++r) acc[m][n][r] = 0.f;

  for (int kb = 0; kb < 4; ++kb) {
    __syncthreads();
#pragma unroll
    for (int i = 0; i < 4; ++i) {
      int idx = i * 256 + t;
      int r = idx >> 3, ck = idx & 7;
      *(uint4*)&As[r][ck * 8] = *(const uint4*)(Ab + (size_t)r * 256 + kb * 64 + ck * 8);
      *(uint4*)&Bs[r][ck * 8] = *(const uint4*)(Bb + (size_t)r * 256 + kb * 64 + ck * 8);
    }
    __syncthreads();
#pragma unroll
    for (int kk = 0; kk < 2; ++kk) {
      bf16x8 af[4], bfr[4];
#pragma unroll
      for (int m = 0; m < 4; ++m) af[m] = *(const bf16x8*)&As[wr * 64 + m * 16 + l16][kk * 32 + quad * 8];
#pragma unroll
      for (int n = 0; n < 4; ++n) bfr[n] = *(const bf16x8*)&Bs[wc * 64 + n * 16 + l16][kk * 32 + quad * 8];
#pragma unroll
      for (int m = 0; m < 4; ++m)
#pragma unroll
        for (int n = 0; n < 4; ++n)
          acc[m][n] = __builtin_amdgcn_mfma_f32_16x16x32_bf16(af[m], bfr[n], acc[m][n], 0, 0, 0);
    }
  }
  size_t cb = (size_t)b * sC;
  size_t rb = (size_t)b * sR;
#pragma unroll
  for (int m = 0; m < 4; ++m)
#pragma unroll
    for (int n = 0; n < 4; ++n)
#pragma unroll
      for (int r = 0; r < 4; ++r) {
        int row = m0 + wr * 64 + m * 16 + quad * 4 + r;
        int col = n0 + wc * 64 + n * 16 + l16;
        size_t idx = (size_t)row * ldc + col;
        if (RESID)
          ((float*)Cout)[cb + idx] = acc[m][n][r] + resid[rb + idx];
        else
          ((unsigned short*)Cout)[cb + idx] = f2bf(acc[m][n][r]);
      }
}

// ---------------- fused attention v5: 512-thr blocks, Br=128, Q in LDS, K-split 2 ------------
// grid 256 = 1 block/CU, 8 waves = 2/SIMD (TLP). Block = (b, qt, kh): Q rows [qt*128,+128),
// K/V rows [kh*2048,+2048). Waves = (wc: i-quarter 0..3) x (wr: j-half 0..1).
// Per iter: stage K(64x256)+V(256x64) (4 uint4/thread each), S^T = K.Q^T (Q frags re-read
// from LDS -> per-wave regs ~190 < 256 cap, no spill), P = exp2 in-register, hi-half shfl
// exchange -> A-frag, O += P.V. Emits unnormalized bf16 O-partial + fp32 l-partial.
__global__ __launch_bounds__(512, 2) void attn(const unsigned short* __restrict__ qk,   // [B][N][512] (q|k)
                                               const unsigned short* __restrict__ vbuf, // [B][C][N]
                                               unsigned short* __restrict__ opart0,     // [B][N][C] bf16 (kh=0)
                                               unsigned short* __restrict__ opart1,     // [B][N][C] bf16 (kh=1)
                                               float* __restrict__ lpart) {             // [B*2][N]
  extern __shared__ __attribute__((aligned(16))) char smem[];  // 139264 B dynamic
  unsigned short* Qs = (unsigned short*)smem;              // [128][264] = 67584 B
  unsigned short* Ks = (unsigned short*)(smem + 67584);    // [64][264]  = 33792 B
  unsigned short* VT = (unsigned short*)(smem + 101376);   // [256][72]  = 36864 B
  float* Lred = (float*)(smem + 138240);                   // [8][32]    = 1024 B

  int xcd = blockIdx.x & 7, slot = blockIdx.x >> 3;
  int b = xcd >> 1;          // XCD pair per batch: K/V halves live in XCD-local L2
  int kh = xcd & 1;
  int i0 = slot * 128;
  int k0 = kh * 32;

  int t = threadIdx.x, w = t >> 6, l = t & 63;
  int l31 = l & 31, hi = l >> 5;
  int wr = w & 1;            // j-half
  int wc = w >> 1;           // i-quarter (0..3)

  const size_t bqk = (size_t)b * NN * 512;
  const size_t bv = (size_t)b * CC * NN;

  // stage Q tile 128x256 once
  {
    const unsigned short* qg = qk + bqk + (size_t)i0 * 512;
#pragma unroll
    for (int it = 0; it < 8; ++it) {
      int idx = it * 512 + t;
      int r = idx >> 5, ck = idx & 31;
      *(uint4*)&Qs[r * 264 + ck * 8] = *(const uint4*)(qg + (size_t)r * 512 + ck * 8);
    }
  }

  floatx16 oacc[8];
#pragma unroll
  for (int cf = 0; cf < 8; ++cf)
#pragma unroll
    for (int r = 0; r < 16; ++r) oacc[cf][r] = 0.f;
  float lacc = 0.f;

  const int qfoff = (wc * 32 + l31) * 264 + hi * 8;   // B-frag: lane = i, elems = c
  const int kfoff = (wr * 32 + l31) * 264 + hi * 8;   // A-frag: lane = j, elems = c
  const int vtoff = wr * 32 + hi * 8;                 // B-frag elems = j

  for (int kt = k0; kt < k0 + 32; ++kt) {
    __syncthreads();
    // stage K-tile [64 j][256 c] and V-tile [256 c][64 j]: 4 uint4/thread each
    {
      const unsigned short* kg = qk + bqk + ((size_t)kt * 64) * 512 + 256;
#pragma unroll
      for (int it = 0; it < 4; ++it) {
        int idx = it * 512 + t;
        int r = idx >> 5, ck = idx & 31;
        *(uint4*)&Ks[r * 264 + ck * 8] = *(const uint4*)(kg + (size_t)r * 512 + ck * 8);
      }
      const unsigned short* vg = vbuf + bv + (size_t)kt * 64;
#pragma unroll
      for (int it = 0; it < 4; ++it) {
        int idx = it * 512 + t;
        int r = idx >> 3, ck = idx & 7;
        *(uint4*)&VT[r * 72 + ck * 8] = *(const uint4*)(vg + (size_t)r * NN + ck * 8);
      }
    }
    __syncthreads();

    // S^T = K . Q^T  (D[m=j][n=i]; lane = i)
    floatx16 st;
#pragma unroll
    for (int r = 0; r < 16; ++r) st[r] = 0.f;
#pragma unroll
    for (int ks = 0; ks < 16; ++ks) {
      bf16x8 kf = *(const bf16x8*)&Ks[kfoff + ks * 16];
      bf16x8 qf = *(const bf16x8*)&Qs[qfoff + ks * 16];
      st = __builtin_amdgcn_mfma_f32_32x32x16_bf16(kf, qf, st, 0, 0, 0);
    }

    // P = exp2(S^T), pack bf16 pairs along j
    u32 pr[8];
#pragma unroll
    for (int k2 = 0; k2 < 8; ++k2) {
      float p0 = __builtin_amdgcn_exp2f(st[2 * k2]);
      float p1 = __builtin_amdgcn_exp2f(st[2 * k2 + 1]);
      lacc += p0 + p1;
      pr[k2] = (u32)f2bf(p0) | ((u32)f2bf(p1) << 16);
    }

    // rearrange into PV A-fragments (j = wr*32 + s*16 + hi*8 + 0..7) via hi-half exchange
    union U { u32 u[4]; bf16x8 v; } a0, a1;
    {
      u32 sA = hi ? pr[0] : pr[2], sB = hi ? pr[1] : pr[3];
      u32 rA = (u32)__shfl_xor((int)sA, 32, 64);
      u32 rB = (u32)__shfl_xor((int)sB, 32, 64);
      a0.u[0] = hi ? rA : pr[0]; a0.u[1] = hi ? rB : pr[1];
      a0.u[2] = hi ? pr[2] : rA; a0.u[3] = hi ? pr[3] : rB;
      sA = hi ? pr[4] : pr[6]; sB = hi ? pr[5] : pr[7];
      rA = (u32)__shfl_xor((int)sA, 32, 64);
      rB = (u32)__shfl_xor((int)sB, 32, 64);
      a1.u[0] = hi ? rA : pr[4]; a1.u[1] = hi ? rB : pr[5];
      a1.u[2] = hi ? pr[6] : rA; a1.u[3] = hi ? pr[7] : rB;
    }

    // O_partial += P . V  (B-frag: lane = c = cf*32+l31, elems = j)
#pragma unroll
    for (int cf = 0; cf < 8; ++cf) {
      const unsigned short* vp = &VT[(cf * 32 + l31) * 72 + vtoff];
      bf16x8 v0 = *(const bf16x8*)vp;
      oacc[cf] = __builtin_amdgcn_mfma_f32_32x32x16_bf16(a0.v, v0, oacc[cf], 0, 0, 0);
      bf16x8 v1 = *(const bf16x8*)(vp + 16);
      oacc[cf] = __builtin_amdgcn_mfma_f32_32x32x16_bf16(a1.v, v1, oacc[cf], 0, 0, 0);
    }
  }

  // ---- epilogue: l reduce, then 2-pass O combine (Of overlays dead Q region, 64 KB) ----
  float l2 = lacc + __shfl_xor(lacc, 32, 64);
  if (hi == 0) Lred[w * 32 + l31] = l2;       // wave w = wc*2 + wr

  unsigned short* ops = kh ? opart1 : opart0;
  size_t pbo = (size_t)b * NN + i0;
  size_t pbl = (size_t)(b * 2 + kh) * NN + i0;
  float* Of = (float*)smem;   // [2 quarters][32 i][256 c] fp32 = 65536 B <= Q region 67584 B

#pragma unroll
  for (int p = 0; p < 2; ++p) {
    __syncthreads();   // pass 0: loop LDS reads + Lred writes done; pass 1: pass-0 stores done
    if (p == 0 && t < 128)
      lpart[pbl + t] = Lred[(t >> 5) * 64 + (t & 31)] + Lred[(t >> 5) * 64 + 32 + (t & 31)];
    if ((wc >> 1) == p && wr == 1) {
#pragma unroll
      for (int cf = 0; cf < 8; ++cf)
#pragma unroll
        for (int r = 0; r < 16; ++r) {
          int il = (r & 3) + 8 * (r >> 2) + 4 * hi;
          Of[(wc & 1) * 8192 + il * 256 + cf * 32 + l31] = oacc[cf][r];
        }
    }
    __syncthreads();
    if ((wc >> 1) == p && wr == 0) {
#pragma unroll
      for (int cf = 0; cf < 8; ++cf)
#pragma unroll
        for (int r = 0; r < 16; ++r) {
          int il = (r & 3) + 8 * (r >> 2) + 4 * hi;
          Of[(wc & 1) * 8192 + il * 256 + cf * 32 + l31] += oacc[cf][r];
        }
    }
    __syncthreads();
    // all 512 threads store this pass's 64 i-rows (16384 elems) as bf16
#pragma unroll
    for (int it = 0; it < 4; ++it) {
      int chunk = it * 512 + t;          // 2048 chunks of 8 elems
      int ilocal = chunk >> 5;           // 0..63
      int qq = ilocal >> 5;              // which quarter of the pass
      int il = ilocal & 31;
      int cc = (chunk & 31) * 8;
      int base = qq * 8192 + il * 256 + cc;
      floatx4 v0 = *(const floatx4*)&Of[base];
      floatx4 v1 = *(const floatx4*)&Of[base + 4];
      union { unsigned short us[8]; uint4 q; } o;
#pragma unroll
      for (int j = 0; j < 4; ++j) {
        o.us[j] = f2bf(v0[j]);
        o.us[4 + j] = f2bf(v1[j]);
      }
      *(uint4*)(ops + (pbo + (size_t)((p * 2 + qq) * 32 + il)) * CC + cc) = o.q;
    }
  }
}

// ---------------- combine the two K-half partials: obuf = (O0+O1)/(l0+l1) ----------------
__global__ __launch_bounds__(256) void attn_combine(const unsigned short* __restrict__ op0,
                                                    const unsigned short* __restrict__ op1,
                                                    const float* __restrict__ lp,
                                                    unsigned short* __restrict__ obuf) {
  int gid = blockIdx.x * 256 + threadIdx.x;   // 524288 threads, 8 elems each
  int e = gid * 8;
  int b = e >> 20;
  int inner = e & 1048575;
  int n = inner >> 8;
  float linv = 1.f / (lp[b * 8192 + n] + lp[b * 8192 + 4096 + n]);
  size_t off = (size_t)b * 1048576 + inner;
  uint4 u0 = *(const uint4*)(op0 + off);
  uint4 u1 = *(const uint4*)(op1 + off);
  const unsigned short* a = (const unsigned short*)&u0;
  const unsigned short* c = (const unsigned short*)&u1;
  union { unsigned short us[8]; uint4 q; } o;
#pragma unroll
  for (int j = 0; j < 8; ++j)
    o.us[j] = f2bf((bf2f(a[j]) + bf2f(c[j])) * linv);
  *(uint4*)(obuf + e) = o.q;
}

extern "C" void kernel_launch(void* const* d_in, const int* in_sizes, int n_in,
                              void* d_out, int out_size, void* d_ws, size_t ws_size,
                              hipStream_t stream) {
  const float* x     = (const float*)d_in[0];
  // d_in[1] = t (unused)
  const float* gamma = (const float*)d_in[2];
  const float* beta  = (const float*)d_in[3];
  const float* wqkv  = (const float*)d_in[4];
  const float* wproj = (const float*)d_in[5];
  float* out = (float*)d_out;

  // Workspace layout (max 42,468,352 B — footprint proven in rounds 1-2-4):
  //   [0,1024)            mr (dead after gn_apply)
  //   [1024, 394240)      wq_bf 384 KB (dead after v-GEMM) — lpart (128 KB) overlays @1024
  //   [394240, 525312)    wp_bf 128 KB (live until proj GEMM)
  //   [525312, 8913920)   normed 8 MB (dead after v-GEMM) — opart0 overlays
  //   [8913920, 25691136) qkbuf 16 MB (dead after attn)   — obuf overlays
  //   [25691136,34079744) vbuf 8 MB
  //   [34079744,42468352) opart1 8 MB
  char* p = (char*)d_ws;
  float* mr               = (float*)(p + 0);
  unsigned short* wq_bf   = (unsigned short*)(p + 1024);
  unsigned short* wp_bf   = (unsigned short*)(p + 394240);
  unsigned short* normed  = (unsigned short*)(p + 525312);
  unsigned short* qkbuf   = (unsigned short*)(p + 8913920);
  unsigned short* vbuf    = (unsigned short*)(p + 25691136);
  unsigned short* opart1  = (unsigned short*)(p + 34079744);
  unsigned short* opart0  = normed;                            // overlay (normed dead after v-GEMM)
  float* lpart            = (float*)(p + 1024);                // overlay (wq_bf dead after v-GEMM)
  unsigned short* obuf    = qkbuf;                             // overlay (qkbuf dead after attn)
  unsigned short* wv_bf   = wq_bf + 512 * 256;

  wconv<<<1024, 256, 0, stream>>>(wqkv, wproj, wq_bf, wp_bf);
  gn_stats<<<128, 256, 0, stream>>>(x, mr);
  gn_apply<<<1024, 256, 0, stream>>>(x, mr, gamma, beta, normed);
  // qk[b][n][o] = normed[b][n][:] . wqkv[o][:]  (o<512)
  gemm_bt<0><<<dim3(128, 4), 256, 0, stream>>>(normed, wq_bf, qkbuf, nullptr,
                                               32, 512, (long)NN * CC, 0L, (long)NN * 512, 0L);
  // v[b][c][n] = wv[c][:] . normed[b][n][:]
  gemm_bt<0><<<dim3(64, 4), 256, 0, stream>>>(wv_bf, normed, vbuf, nullptr,
                                              2, 4096, 0L, (long)NN * CC, (long)CC * NN, 0L);
  attn<<<256, 512, 139264, stream>>>(qkbuf, vbuf, opart0, opart1, lpart);
  attn_combine<<<2048, 256, 0, stream>>>(opart0, opart1, lpart, obuf);
  // out[b][co][n] = wproj[co][:] . obuf[b][n][:] + x[b][co][n]
  gemm_bt<1><<<dim3(64, 4), 256, 0, stream>>>(wp_bf, obuf, out, x,
                                              2, 4096, 0L, (long)NN * CC, (long)CC * NN, (long)CC * NN);
}